// Round 1
// baseline (114.917 us; speedup 1.0000x reference)
//
#include <hip/hip_runtime.h>
#include <math.h>

#define ZZ 128
#define CC 12
#define HH 512
#define NB 4096

// ---------------------------------------------------------------------------
// Kernel 1: edge weights M[j,i] = adj[j,i] ? exp(-w0 * tt[j,i]) : 0
// ---------------------------------------------------------------------------
__global__ void k_edge_weights(const int* __restrict__ adj, const int* __restrict__ tt,
                               const float* __restrict__ w0p, float* __restrict__ M) {
    int e = blockIdx.x * blockDim.x + threadIdx.x;
    if (e < ZZ * ZZ) {
        float w0 = w0p[0];
        M[e] = adj[e] ? expf(-w0 * (float)tt[e]) : 0.f;
    }
}

// ---------------------------------------------------------------------------
// Kernel 2: next[b,i] = sum_c obs[b,i,c]*w[c] + sum_j act[b,j,i]*M[j,i]
// grid = NB blocks, block = ZZ threads (i = threadIdx.x). Coalesced over i.
// ---------------------------------------------------------------------------
__global__ void k_next(const float* __restrict__ obs, const float* __restrict__ act,
                       const float* __restrict__ M, const float* __restrict__ w0p,
                       float* __restrict__ out_next) {
    __shared__ float wsh[CC];
    int b = blockIdx.x;
    int i = threadIdx.x;
    if (i < CC) wsh[i] = expf(-w0p[0] * (float)i);
    __syncthreads();

    float acc = 0.f;
    const float* orow = obs + ((size_t)b * ZZ + i) * CC;
#pragma unroll
    for (int c = 0; c < CC; ++c) acc += orow[c] * wsh[c];

    const float* acol = act + (size_t)b * ZZ * ZZ + i;
#pragma unroll 4
    for (int j = 0; j < ZZ; ++j) acc += acol[(size_t)j * ZZ] * M[j * ZZ + i];

    out_next[(size_t)b * ZZ + i] = acc;
}

// ---------------------------------------------------------------------------
// Kernel 3: tiled fp32 GEMM  C[M,N] = relu?(A[M,K] @ B[K,N] + bias[N])
// 64x64 tile, BK=32, 256 threads, 4x4 microtile per thread.
// ---------------------------------------------------------------------------
#define BM 64
#define BN 64
#define BK 32
#define LDSP 68   // padded row stride (words); multiple of 4 for b128 alignment

__global__ __launch_bounds__(256) void k_gemm(const float* __restrict__ A,
                                              const float* __restrict__ B,
                                              const float* __restrict__ bias,
                                              float* __restrict__ C,
                                              int Mdim, int Ndim, int Kdim, int doRelu) {
    __shared__ float As[BK * LDSP];   // stored transposed: As[k][m]
    __shared__ float Bs[BK * LDSP];   // Bs[k][n]
    int tid = threadIdx.x;
    int tx = tid % 16;      // col group (4 cols each)
    int ty = tid / 16;      // row group (4 rows each)
    int m0 = blockIdx.y * BM, n0 = blockIdx.x * BN;

    float acc[4][4] = {{0.f}};

    for (int k0 = 0; k0 < Kdim; k0 += BK) {
        // load A tile (BM x BK), store transposed As[k][m]
#pragma unroll
        for (int it = 0; it < (BM * BK) / 256; ++it) {
            int idx = tid + it * 256;
            int r = idx / BK, c = idx % BK;
            As[c * LDSP + r] = A[(size_t)(m0 + r) * Kdim + k0 + c];
        }
        // load B tile (BK x BN)
#pragma unroll
        for (int it = 0; it < (BK * BN) / 256; ++it) {
            int idx = tid + it * 256;
            int r = idx / BN, c = idx % BN;
            Bs[r * LDSP + c] = B[(size_t)(k0 + r) * Ndim + n0 + c];
        }
        __syncthreads();

#pragma unroll
        for (int k = 0; k < BK; ++k) {
            float4 a4 = *(const float4*)&As[k * LDSP + ty * 4];
            float4 b4 = *(const float4*)&Bs[k * LDSP + tx * 4];
            float av[4] = {a4.x, a4.y, a4.z, a4.w};
            float bv[4] = {b4.x, b4.y, b4.z, b4.w};
#pragma unroll
            for (int mi = 0; mi < 4; ++mi)
#pragma unroll
                for (int ni = 0; ni < 4; ++ni)
                    acc[mi][ni] += av[mi] * bv[ni];
        }
        __syncthreads();
    }

#pragma unroll
    for (int mi = 0; mi < 4; ++mi) {
        int row = m0 + ty * 4 + mi;
#pragma unroll
        for (int ni = 0; ni < 4; ++ni) {
            int col = n0 + tx * 4 + ni;
            float v = acc[mi][ni] + bias[col];
            if (doRelu) v = fmaxf(v, 0.f);
            C[(size_t)row * Ndim + col] = v;
        }
    }
}

// ---------------------------------------------------------------------------
// Kernel 4: out[b] = dot(x2[b,:], Wf) + bf   (one wave per b)
// ---------------------------------------------------------------------------
__global__ void k_final(const float* __restrict__ x2, const float* __restrict__ Wf,
                        const float* __restrict__ bfp, float* __restrict__ out) {
    int wid = (blockIdx.x * blockDim.x + threadIdx.x) / 64;
    int lane = threadIdx.x % 64;
    const float* row = x2 + (size_t)wid * HH;
    float p = 0.f;
#pragma unroll
    for (int u = 0; u < HH / 64; ++u)
        p += row[u * 64 + lane] * Wf[u * 64 + lane];
#pragma unroll
    for (int off = 32; off; off >>= 1)
        p += __shfl_down(p, off);
    if (lane == 0) out[wid] = p + bfp[0];
}

extern "C" void kernel_launch(void* const* d_in, const int* in_sizes, int n_in,
                              void* d_out, int out_size, void* d_ws, size_t ws_size,
                              hipStream_t stream) {
    const float* obs = (const float*)d_in[0];
    const float* act = (const float*)d_in[1];
    const float* w0  = (const float*)d_in[2];
    const float* W1  = (const float*)d_in[3];
    const float* b1  = (const float*)d_in[4];
    const float* W2  = (const float*)d_in[5];
    const float* b2  = (const float*)d_in[6];
    const float* Wf  = (const float*)d_in[7];
    const float* bf  = (const float*)d_in[8];
    const int* adj   = (const int*)d_in[9];
    const int* tt    = (const int*)d_in[10];

    float* out = (float*)d_out;           // [0:NB) symbolic_val, [NB : NB+NB*ZZ) next_state
    float* ws  = (float*)d_ws;

    float* M   = ws;                       // ZZ*ZZ
    float* x1  = ws + ZZ * ZZ;             // NB*HH
    float* x2  = x1 + (size_t)NB * HH;     // NB*HH
    float* nxt = out + NB;                 // next_state lives directly in d_out

    k_edge_weights<<<(ZZ * ZZ + 255) / 256, 256, 0, stream>>>(adj, tt, w0, M);
    k_next<<<NB, ZZ, 0, stream>>>(obs, act, M, w0, nxt);

    dim3 g1(HH / BN, NB / BM);
    k_gemm<<<g1, 256, 0, stream>>>(nxt, W1, b1, x1, NB, HH, ZZ, 1);
    k_gemm<<<g1, 256, 0, stream>>>(x1, W2, b2, x2, NB, HH, HH, 1);

    k_final<<<NB / 4, 256, 0, stream>>>(x2, Wf, bf, out);
}